// Round 1
// baseline (568.964 us; speedup 1.0000x reference)
//
#include <hip/hip_runtime.h>

#define B 256
#define D 128
#define NEG 1024
#define SAMPLES 300000
#define TEMP 0.07f
#define EPS 1e-12f

// output layout: scores [4,B,1+NEG] | audio_memory_new [SAMPLES,D] | video_memory_new [SAMPLES,D]
constexpr int SCORES_ELEMS = 4 * B * (NEG + 1);            // 1,049,600
constexpr int MEM_ELEMS    = SAMPLES * D;                   // 38,400,000

__device__ inline float wave_reduce_sum(float x) {
    // 64-lane butterfly
    #pragma unroll
    for (int off = 32; off > 0; off >>= 1) x += __shfl_xor(x, off, 64);
    return x;
}

// One wave per batch row: normalize embeddings, positive scores, momentum rows.
__global__ __launch_bounds__(64) void prep_kernel(
    const float* __restrict__ audio_emb, const float* __restrict__ video_emb,
    const float* __restrict__ a_mem, const float* __restrict__ v_mem,
    const int* __restrict__ indices,
    float* __restrict__ na, float* __restrict__ nv,
    float* __restrict__ new_a, float* __restrict__ new_v,
    float* __restrict__ scores)
{
    const int b = blockIdx.x;
    const int l = threadIdx.x;  // lane handles elements [2l, 2l+1]

    float2 a = ((const float2*)(audio_emb + b * D))[l];
    float2 v = ((const float2*)(video_emb + b * D))[l];

    float sa = wave_reduce_sum(a.x * a.x + a.y * a.y);
    float sv = wave_reduce_sum(v.x * v.x + v.y * v.y);
    float ira = 1.0f / fmaxf(sqrtf(sa), EPS);
    float irv = 1.0f / fmaxf(sqrtf(sv), EPS);
    float2 naf = {a.x * ira, a.y * ira};
    float2 nvf = {v.x * irv, v.y * irv};
    ((float2*)(na + b * D))[l] = naf;
    ((float2*)(nv + b * D))[l] = nvf;

    const long long idx = (long long)indices[b];
    float2 pa = ((const float2*)(a_mem + idx * D))[l];
    float2 pv = ((const float2*)(v_mem + idx * D))[l];

    // positive scores: order = [pos_v·na, pos_a·nv, pos_a·na, pos_v·nv]
    float d0 = wave_reduce_sum(pv.x * naf.x + pv.y * naf.y);
    float d1 = wave_reduce_sum(pa.x * nvf.x + pa.y * nvf.y);
    float d2 = wave_reduce_sum(pa.x * naf.x + pa.y * naf.y);
    float d3 = wave_reduce_sum(pv.x * nvf.x + pv.y * nvf.y);
    if (l == 0) {
        scores[(0 * B + b) * (NEG + 1)] = d0 / TEMP;
        scores[(1 * B + b) * (NEG + 1)] = d1 / TEMP;
        scores[(2 * B + b) * (NEG + 1)] = d2 / TEMP;
        scores[(3 * B + b) * (NEG + 1)] = d3 / TEMP;
    }

    // momentum update rows (normalized)
    float2 ta = {0.5f * (pa.x + naf.x), 0.5f * (pa.y + naf.y)};
    float2 tv = {0.5f * (pv.x + nvf.x), 0.5f * (pv.y + nvf.y)};
    float sta = wave_reduce_sum(ta.x * ta.x + ta.y * ta.y);
    float stv = wave_reduce_sum(tv.x * tv.x + tv.y * tv.y);
    float irta = 1.0f / fmaxf(sqrtf(sta), EPS);
    float irtv = 1.0f / fmaxf(sqrtf(stv), EPS);
    ta.x *= irta; ta.y *= irta;
    tv.x *= irtv; tv.y *= irtv;
    ((float2*)(new_a + b * D))[l] = ta;
    ((float2*)(new_v + b * D))[l] = tv;
}

// Negative scores: thread per (b, n). Each gathered row read once, feeds 2 dots.
__global__ __launch_bounds__(256) void neg_scores_kernel(
    const float* __restrict__ a_mem, const float* __restrict__ v_mem,
    const int* __restrict__ indices, const int* __restrict__ neg_samples,
    const float* __restrict__ na, const float* __restrict__ nv,
    float* __restrict__ scores)
{
    const int b = blockIdx.y;
    const int n = blockIdx.x * blockDim.x + threadIdx.x;

    __shared__ float4 na_s[D / 4];
    __shared__ float4 nv_s[D / 4];
    if (threadIdx.x < D / 4)
        na_s[threadIdx.x] = ((const float4*)(na + b * D))[threadIdx.x];
    else if (threadIdx.x < D / 2)
        nv_s[threadIdx.x - D / 4] = ((const float4*)(nv + b * D))[threadIdx.x - D / 4];
    __syncthreads();

    const int pos = indices[b];
    const int ns  = neg_samples[b * NEG + n];
    const long long ni = (long long)ns + (ns >= pos ? 1 : 0);  // skip positive

    const float4* ra = (const float4*)(a_mem + ni * D);
    const float4* rv = (const float4*)(v_mem + ni * D);

    float s0 = 0.f, s1 = 0.f, s2 = 0.f, s3 = 0.f;
    #pragma unroll
    for (int k = 0; k < D / 4; ++k) {
        float4 A = ra[k];
        float4 V = rv[k];
        float4 NA = na_s[k];
        float4 NV = nv_s[k];
        s0 += V.x * NA.x + V.y * NA.y + V.z * NA.z + V.w * NA.w;  // neg_v · na
        s1 += A.x * NV.x + A.y * NV.y + A.z * NV.z + A.w * NV.w;  // neg_a · nv
        s2 += A.x * NA.x + A.y * NA.y + A.z * NA.z + A.w * NA.w;  // neg_a · na
        s3 += V.x * NV.x + V.y * NV.y + V.z * NV.z + V.w * NV.w;  // neg_v · nv
    }
    scores[(0 * B + b) * (NEG + 1) + 1 + n] = s0 / TEMP;
    scores[(1 * B + b) * (NEG + 1) + 1 + n] = s1 / TEMP;
    scores[(2 * B + b) * (NEG + 1) + 1 + n] = s2 / TEMP;
    scores[(3 * B + b) * (NEG + 1) + 1 + n] = s3 / TEMP;
}

// Flat copy of both memory banks into the output (one float4 per thread).
__global__ __launch_bounds__(256) void copy_kernel(
    const float4* __restrict__ a_mem, const float4* __restrict__ v_mem,
    float4* __restrict__ out_a, float4* __restrict__ out_v, int n4)
{
    int i = blockIdx.x * blockDim.x + threadIdx.x;
    if (i < n4) {
        out_a[i] = a_mem[i];
    } else {
        i -= n4;
        if (i < n4) out_v[i] = v_mem[i];
    }
}

// Scatter updated rows; last occurrence wins on duplicate indices (numpy semantics).
__global__ __launch_bounds__(128) void scatter_kernel(
    const int* __restrict__ indices,
    const float* __restrict__ new_a, const float* __restrict__ new_v,
    float* __restrict__ out_a, float* __restrict__ out_v)
{
    const int b = blockIdx.x;
    const int t = threadIdx.x;  // D threads
    const int myidx = indices[b];

    __shared__ int skip;
    if (t == 0) skip = 0;
    __syncthreads();
    for (int b2 = b + 1 + t; b2 < B; b2 += blockDim.x)
        if (indices[b2] == myidx) skip = 1;  // benign race: only ever set to 1
    __syncthreads();
    if (skip) return;

    out_a[(long long)myidx * D + t] = new_a[b * D + t];
    out_v[(long long)myidx * D + t] = new_v[b * D + t];
}

extern "C" void kernel_launch(void* const* d_in, const int* in_sizes, int n_in,
                              void* d_out, int out_size, void* d_ws, size_t ws_size,
                              hipStream_t stream) {
    const float* audio_emb   = (const float*)d_in[0];
    const float* video_emb   = (const float*)d_in[1];
    const float* a_mem       = (const float*)d_in[2];
    const float* v_mem       = (const float*)d_in[3];
    const int*   indices     = (const int*)d_in[4];
    const int*   neg_samples = (const int*)d_in[5];

    float* out    = (float*)d_out;
    float* scores = out;
    float* out_a  = out + SCORES_ELEMS;
    float* out_v  = out_a + MEM_ELEMS;

    float* ws    = (float*)d_ws;
    float* na    = ws;
    float* nv    = na + B * D;
    float* new_a = nv + B * D;
    float* new_v = new_a + B * D;

    prep_kernel<<<B, 64, 0, stream>>>(audio_emb, video_emb, a_mem, v_mem, indices,
                                      na, nv, new_a, new_v, scores);

    dim3 g2(NEG / 256, B);
    neg_scores_kernel<<<g2, 256, 0, stream>>>(a_mem, v_mem, indices, neg_samples,
                                              na, nv, scores);

    const int n4 = MEM_ELEMS / 4;  // 9,600,000 float4 per bank
    copy_kernel<<<(2 * n4) / 256, 256, 0, stream>>>((const float4*)a_mem, (const float4*)v_mem,
                                                    (float4*)out_a, (float4*)out_v, n4);

    scatter_kernel<<<B, D, 0, stream>>>(indices, new_a, new_v, out_a, out_v);
}

// Round 2
// 541.391 us; speedup vs baseline: 1.0509x; 1.0509x over previous
//
#include <hip/hip_runtime.h>

#define B 256
#define D 128
#define NEG 1024
#define SAMPLES 300000
#define TEMP 0.07f
#define EPS 1e-12f

// output layout: scores [4,B,1+NEG] | audio_memory_new [SAMPLES,D] | video_memory_new [SAMPLES,D]
constexpr int SCORES_ELEMS = 4 * B * (NEG + 1);            // 1,049,600
constexpr int MEM_ELEMS    = SAMPLES * D;                   // 38,400,000

__device__ inline float wave_reduce_sum(float x) {
    // 64-lane butterfly
    #pragma unroll
    for (int off = 32; off > 0; off >>= 1) x += __shfl_xor(x, off, 64);
    return x;
}

// One wave per batch row: normalize embeddings, positive scores, momentum rows.
__global__ __launch_bounds__(64) void prep_kernel(
    const float* __restrict__ audio_emb, const float* __restrict__ video_emb,
    const float* __restrict__ a_mem, const float* __restrict__ v_mem,
    const int* __restrict__ indices,
    float* __restrict__ na, float* __restrict__ nv,
    float* __restrict__ new_a, float* __restrict__ new_v,
    float* __restrict__ scores)
{
    const int b = blockIdx.x;
    const int l = threadIdx.x;  // lane handles elements [2l, 2l+1]

    float2 a = ((const float2*)(audio_emb + b * D))[l];
    float2 v = ((const float2*)(video_emb + b * D))[l];

    float sa = wave_reduce_sum(a.x * a.x + a.y * a.y);
    float sv = wave_reduce_sum(v.x * v.x + v.y * v.y);
    float ira = 1.0f / fmaxf(sqrtf(sa), EPS);
    float irv = 1.0f / fmaxf(sqrtf(sv), EPS);
    float2 naf = {a.x * ira, a.y * ira};
    float2 nvf = {v.x * irv, v.y * irv};
    ((float2*)(na + b * D))[l] = naf;
    ((float2*)(nv + b * D))[l] = nvf;

    const long long idx = (long long)indices[b];
    float2 pa = ((const float2*)(a_mem + idx * D))[l];
    float2 pv = ((const float2*)(v_mem + idx * D))[l];

    // positive scores: order = [pos_v·na, pos_a·nv, pos_a·na, pos_v·nv]
    float d0 = wave_reduce_sum(pv.x * naf.x + pv.y * naf.y);
    float d1 = wave_reduce_sum(pa.x * nvf.x + pa.y * nvf.y);
    float d2 = wave_reduce_sum(pa.x * naf.x + pa.y * naf.y);
    float d3 = wave_reduce_sum(pv.x * nvf.x + pv.y * nvf.y);
    if (l == 0) {
        scores[(0 * B + b) * (NEG + 1)] = d0 / TEMP;
        scores[(1 * B + b) * (NEG + 1)] = d1 / TEMP;
        scores[(2 * B + b) * (NEG + 1)] = d2 / TEMP;
        scores[(3 * B + b) * (NEG + 1)] = d3 / TEMP;
    }

    // momentum update rows (normalized)
    float2 ta = {0.5f * (pa.x + naf.x), 0.5f * (pa.y + naf.y)};
    float2 tv = {0.5f * (pv.x + nvf.x), 0.5f * (pv.y + nvf.y)};
    float sta = wave_reduce_sum(ta.x * ta.x + ta.y * ta.y);
    float stv = wave_reduce_sum(tv.x * tv.x + tv.y * tv.y);
    float irta = 1.0f / fmaxf(sqrtf(sta), EPS);
    float irtv = 1.0f / fmaxf(sqrtf(stv), EPS);
    ta.x *= irta; ta.y *= irta;
    tv.x *= irtv; tv.y *= irtv;
    ((float2*)(new_a + b * D))[l] = ta;
    ((float2*)(new_v + b * D))[l] = tv;
}

// Negative scores: HALF-WAVE (32 lanes) per gathered row. One float4/lane covers
// the full 512 B row -> every global load instruction is a fully-coalesced,
// fully-consumed row read (the two wave halves do two different rows).
// 4 dots per row via 5-stage butterfly confined to each 32-lane half.
__global__ __launch_bounds__(256) void neg_scores_kernel(
    const float* __restrict__ a_mem, const float* __restrict__ v_mem,
    const int* __restrict__ indices, const int* __restrict__ neg_samples,
    const float* __restrict__ na, const float* __restrict__ nv,
    float* __restrict__ scores)
{
    const int b    = blockIdx.y;
    const int hw   = threadIdx.x >> 5;   // half-wave id 0..7
    const int lane = threadIdx.x & 31;
    const int n    = blockIdx.x * 8 + hw;  // negative index in [0,NEG)

    const int pos = indices[b];
    const int ns  = neg_samples[b * NEG + n];
    const long long ni = (long long)ns + (ns >= pos ? 1 : 0);  // skip positive

    float4 A  = ((const float4*)(a_mem + ni * D))[lane];
    float4 V  = ((const float4*)(v_mem + ni * D))[lane];
    float4 NA = ((const float4*)(na + (long long)b * D))[lane];
    float4 NV = ((const float4*)(nv + (long long)b * D))[lane];

    float s0 = V.x * NA.x + V.y * NA.y + V.z * NA.z + V.w * NA.w;  // neg_v · na
    float s1 = A.x * NV.x + A.y * NV.y + A.z * NV.z + A.w * NV.w;  // neg_a · nv
    float s2 = A.x * NA.x + A.y * NA.y + A.z * NA.z + A.w * NA.w;  // neg_a · na
    float s3 = V.x * NV.x + V.y * NV.y + V.z * NV.z + V.w * NV.w;  // neg_v · nv

    #pragma unroll
    for (int off = 16; off > 0; off >>= 1) {   // stays within each 32-lane half
        s0 += __shfl_xor(s0, off, 64);
        s1 += __shfl_xor(s1, off, 64);
        s2 += __shfl_xor(s2, off, 64);
        s3 += __shfl_xor(s3, off, 64);
    }
    if (lane == 0) {
        scores[(0 * B + b) * (NEG + 1) + 1 + n] = s0 / TEMP;
        scores[(1 * B + b) * (NEG + 1) + 1 + n] = s1 / TEMP;
        scores[(2 * B + b) * (NEG + 1) + 1 + n] = s2 / TEMP;
        scores[(3 * B + b) * (NEG + 1) + 1 + n] = s3 / TEMP;
    }
}

// Flat copy of both memory banks into the output (one float4 per thread).
__global__ __launch_bounds__(256) void copy_kernel(
    const float4* __restrict__ a_mem, const float4* __restrict__ v_mem,
    float4* __restrict__ out_a, float4* __restrict__ out_v, int n4)
{
    int i = blockIdx.x * blockDim.x + threadIdx.x;
    if (i < n4) {
        out_a[i] = a_mem[i];
    } else {
        i -= n4;
        if (i < n4) out_v[i] = v_mem[i];
    }
}

// Scatter updated rows; last occurrence wins on duplicate indices (numpy semantics).
__global__ __launch_bounds__(128) void scatter_kernel(
    const int* __restrict__ indices,
    const float* __restrict__ new_a, const float* __restrict__ new_v,
    float* __restrict__ out_a, float* __restrict__ out_v)
{
    const int b = blockIdx.x;
    const int t = threadIdx.x;  // D threads
    const int myidx = indices[b];

    __shared__ int skip;
    if (t == 0) skip = 0;
    __syncthreads();
    for (int b2 = b + 1 + t; b2 < B; b2 += blockDim.x)
        if (indices[b2] == myidx) skip = 1;  // benign race: only ever set to 1
    __syncthreads();
    if (skip) return;

    out_a[(long long)myidx * D + t] = new_a[b * D + t];
    out_v[(long long)myidx * D + t] = new_v[b * D + t];
}

extern "C" void kernel_launch(void* const* d_in, const int* in_sizes, int n_in,
                              void* d_out, int out_size, void* d_ws, size_t ws_size,
                              hipStream_t stream) {
    const float* audio_emb   = (const float*)d_in[0];
    const float* video_emb   = (const float*)d_in[1];
    const float* a_mem       = (const float*)d_in[2];
    const float* v_mem       = (const float*)d_in[3];
    const int*   indices     = (const int*)d_in[4];
    const int*   neg_samples = (const int*)d_in[5];

    float* out    = (float*)d_out;
    float* scores = out;
    float* out_a  = out + SCORES_ELEMS;
    float* out_v  = out_a + MEM_ELEMS;

    float* ws    = (float*)d_ws;
    float* na    = ws;
    float* nv    = na + B * D;
    float* new_a = nv + B * D;
    float* new_v = new_a + B * D;

    prep_kernel<<<B, 64, 0, stream>>>(audio_emb, video_emb, a_mem, v_mem, indices,
                                      na, nv, new_a, new_v, scores);

    dim3 g2(NEG / 8, B);  // half-wave per row, 8 rows per 256-thread block
    neg_scores_kernel<<<g2, 256, 0, stream>>>(a_mem, v_mem, indices, neg_samples,
                                              na, nv, scores);

    const int n4 = MEM_ELEMS / 4;  // 9,600,000 float4 per bank
    copy_kernel<<<(2 * n4) / 256, 256, 0, stream>>>((const float4*)a_mem, (const float4*)v_mem,
                                                    (float4*)out_a, (float4*)out_v, n4);

    scatter_kernel<<<B, D, 0, stream>>>(indices, new_a, new_v, out_a, out_v);
}